// Round 4
// baseline (4704.612 us; speedup 1.0000x reference)
//
#include <hip/hip_runtime.h>
#include <hip/hip_cooperative_groups.h>
#include <math.h>

#define TSTEPS 63
#define BB 64
#define ED 512
#define HD 1024
#define VV 32000
#define GG 4096            // 4*HD
#define NROWS 4032         // TSTEPS*BB
#define MPAD 4096          // padded row count for MFMA tiles
#define NCH 500            // 64-col LSE chunks (32000/64)
#define HSLOT 65536        // 64*1024 (one h-state slot, shorts)

typedef __attribute__((ext_vector_type(8))) short short8;
typedef __attribute__((ext_vector_type(4))) float f32x4;

__device__ __forceinline__ float sigf(float x) { return 1.0f / (1.0f + __expf(-x)); }

__device__ __forceinline__ short f2bf(float f) {
  unsigned u = __float_as_uint(f);
  unsigned r = (u + 0x7FFFu + ((u >> 16) & 1u)) >> 16;
  return (short)r;
}
__device__ __forceinline__ float bf2f(short h) {
  return __uint_as_float(((unsigned)(unsigned short)h) << 16);
}

#define GLOAD_LDS(g, l) \
  __builtin_amdgcn_global_load_lds((const __attribute__((address_space(1))) void*)(g), \
                                   (__attribute__((address_space(3))) void*)(l), 16, 0, 0)

// ---------------- fp32 -> bf16 convert ----------------
__global__ __launch_bounds__(256)
void cvt_f2b_k(const float* __restrict__ src, short* __restrict__ dst) {
  int i = (blockIdx.x * 256 + threadIdx.x) * 4;
  float4 v = *(const float4*)(src + i);
  short4 o;
  o.x = f2bf(v.x); o.y = f2bf(v.y); o.z = f2bf(v.z); o.w = f2bf(v.w);
  *(short4*)(dst + i) = o;
}

// ---------------- gather emb rows by dec, convert to bf16 ----------------
__global__ __launch_bounds__(256)
void gather_emb_k(const int* __restrict__ dec, const float* __restrict__ emb,
                  short* __restrict__ XembB) {
  int idx = blockIdx.x * 256 + threadIdx.x;
  int r = idx >> 7, cc = (idx & 127) * 4;
  int src = dec[r];
  float4 v = *(const float4*)(emb + (size_t)src * ED + cc);
  short4 o;
  o.x = f2bf(v.x); o.y = f2bf(v.y); o.z = f2bf(v.z); o.w = f2bf(v.w);
  *(short4*)(XembB + (size_t)r * ED + cc) = o;
}

// ---------------- init h-slots (bf16) ----------------
__global__ __launch_bounds__(256)
void init_state2_k(const float* __restrict__ h0, short* __restrict__ h0buf,
                   short* __restrict__ H1b) {
  int i = blockIdx.x * 256 + threadIdx.x;   // 0..65535
  h0buf[HSLOT + i] = f2bf(h0[i]);           // layer0 h init -> slot 1 (read at t=0)
  H1b[i] = f2bf(h0[BB * HD + i]);           // layer1 h init -> H1 slot -1
}

__global__ __launch_bounds__(256)
void bias_sum_k(const float* __restrict__ a, const float* __restrict__ b,
                float* __restrict__ s) {
  int i = blockIdx.x * 256 + threadIdx.x;
  s[i] = a[i] + b[i];
}

// ---------------- zero pad rows 4032..4095 of logits-view H1 ----------------
__global__ __launch_bounds__(256)
void pad_h1b_k(short* __restrict__ dst) {
  int i = (blockIdx.x * 256 + threadIdx.x) * 4;
  short4 z; z.x = z.y = z.z = z.w = 0;
  *(short4*)(dst + i) = z;
}

__global__ void zero_out_k(float* __restrict__ out) {
  if (threadIdx.x == 0) out[0] = 0.f;
}

// ---------------- shared MFMA K-loop (validated round 2) ----------------
template<int NK>
__device__ __forceinline__ void mfma_loop(const short* __restrict__ Abase, int lda,
                                          const short* __restrict__ Bbase, int ldb,
                                          short* lds_a, short* lds_b,
                                          f32x4 acc[4][4]) {
  const int tid = threadIdx.x;
  const int l = tid & 63;
  const int w = tid >> 6;
  const int wm = w >> 1, wn = w & 1;
  const int p = tid & 7;
  const int rbase = tid >> 3;

  for (int kt = 0; kt < NK; kt++) {
#pragma unroll
    for (int it = 0; it < 4; it++) {
      int row = it * 32 + rbase;
      int ch = p ^ (row & 7);
      const short* ga = Abase + (size_t)row * lda + kt * 64 + ch * 8;
      const short* gb = Bbase + (size_t)row * ldb + kt * 64 + ch * 8;
      short* la = lds_a + it * 2048 + tid * 8;
      short* lb = lds_b + it * 2048 + tid * 8;
      GLOAD_LDS(ga, la);
      GLOAD_LDS(gb, lb);
    }
    asm volatile("s_waitcnt vmcnt(0)" ::: "memory");
    __syncthreads();

    short8 af[4][2], bf[4][2];
#pragma unroll
    for (int m = 0; m < 4; m++) {
#pragma unroll
      for (int ks = 0; ks < 2; ks++) {
        int ra = wm * 64 + m * 16 + (l & 15);
        int ca = (ks * 4 + (l >> 4)) ^ (ra & 7);
        af[m][ks] = *(const short8*)(lds_a + ra * 64 + ca * 8);
        int rb = wn * 64 + m * 16 + (l & 15);
        int cb = (ks * 4 + (l >> 4)) ^ (rb & 7);
        bf[m][ks] = *(const short8*)(lds_b + rb * 64 + cb * 8);
      }
    }
#pragma unroll
    for (int ks = 0; ks < 2; ks++)
#pragma unroll
      for (int m = 0; m < 4; m++)
#pragma unroll
        for (int n = 0; n < 4; n++)
          acc[m][n] = __builtin_amdgcn_mfma_f32_16x16x32_bf16(af[m][ks], bf[n][ks],
                                                              acc[m][n], 0, 0, 0);
    __syncthreads();
  }
}

// ---------------- X0 = XembB @ Wih0B^T + bih0 + bhh0 (MFMA) ----------------
__global__ __launch_bounds__(256)
void x0_mfma_k(const short* __restrict__ XembB, const short* __restrict__ Wih0B,
               const float* __restrict__ bih0, const float* __restrict__ bhh0,
               float* __restrict__ X0) {
  __shared__ short lds_a[128 * 64];
  __shared__ short lds_b[128 * 64];
  f32x4 acc[4][4];
#pragma unroll
  for (int m = 0; m < 4; m++)
#pragma unroll
    for (int n = 0; n < 4; n++)
#pragma unroll
      for (int q = 0; q < 4; q++) acc[m][n][q] = 0.f;

  mfma_loop<8>(XembB + (size_t)blockIdx.x * 128 * ED, ED,
               Wih0B + (size_t)blockIdx.y * 128 * ED, ED, lds_a, lds_b, acc);

  const int l = threadIdx.x & 63;
  const int w = threadIdx.x >> 6;
  const int wm = w >> 1, wn = w & 1;
#pragma unroll
  for (int m = 0; m < 4; m++)
#pragma unroll
    for (int r = 0; r < 4; r++) {
      int row = blockIdx.x * 128 + wm * 64 + m * 16 + (l >> 4) * 4 + r;
#pragma unroll
      for (int n = 0; n < 4; n++) {
        int col = blockIdx.y * 128 + wn * 64 + n * 16 + (l & 15);
        X0[(size_t)row * GG + col] = acc[m][n][r] + bih0[col] + bhh0[col];
      }
    }
}

// ---------------- persistent cooperative 63-step 2-layer LSTM (v2) ----------
// 128 blocks: 0..63 layer0, 64..127 layer1; block g owns j-slice [g*16, g*16+16).
// Wave = gate. All MFMA fragments loaded DIRECTLY global->VGPR (L2-hot, no LDS,
// no barriers in K-loop). Pipelined: phase ph runs layer0(t=ph) || layer1(t=ph-1).
__global__ __launch_bounds__(256, 1)
void recurrence_k(const float* __restrict__ X0, const float* __restrict__ bsum1,
                  const short* __restrict__ Wh0b, const short* __restrict__ Wi1b,
                  const short* __restrict__ Wh1b, short* __restrict__ h0buf,
                  short* __restrict__ H1b, const float* __restrict__ c0all) {
  cooperative_groups::grid_group grid = cooperative_groups::this_grid();
  __shared__ float Gs[64][4][16];          // [b][gate][j-offset], 16 KB
  const int tid = threadIdx.x;
  const int l  = tid & 63;
  const int w  = tid >> 6;                 // gate index
  const int li = l & 15;
  const int kc = l >> 4;
  const bool isL0 = (blockIdx.x < 64);
  const int g  = isL0 ? (int)blockIdx.x : (int)blockIdx.x - 64;
  const int jb = g * 16;

  // c-state in registers of the cell-thread mapping
  const int cc = tid & 15, bq = tid >> 4;
  float creg[4];
#pragma unroll
  for (int r = 0; r < 4; r++)
    creg[r] = c0all[(isL0 ? 0 : BB * HD) + (size_t)(r * 16 + bq) * HD + jb + cc];

  const short* Wb0 = Wh0b + (size_t)(w * HD + jb) * HD;   // layer0 W rows for this wave
  const short* Wi1w = Wi1b + (size_t)(w * HD + jb) * HD;  // layer1 Wih rows
  const short* Wh1w = Wh1b + (size_t)(w * HD + jb) * HD;  // layer1 Whh rows

  for (int ph = 0; ph < 64; ph++) {
    if (isL0 && ph < TSTEPS) {
      // ======== layer 0, step t: G_w = h0(t-1) @ Whh0[w*HD+jb .. +16]^T ========
      const int t = ph;
      const short* Ap = h0buf + ((t + 1) & 1) * HSLOT;
      f32x4 acc[4];
#pragma unroll
      for (int m = 0; m < 4; m++)
#pragma unroll
        for (int q = 0; q < 4; q++) acc[m][q] = 0.f;

      short8 aE[4], aO[4], bE, bO;
#pragma unroll
      for (int m = 0; m < 4; m++)
        aE[m] = *(const short8*)(Ap + (size_t)(m * 16 + li) * HD + kc * 8);
      bE = *(const short8*)(Wb0 + (size_t)li * HD + kc * 8);
#pragma unroll
      for (int kt = 0; kt < 32; kt += 2) {
#pragma unroll
        for (int m = 0; m < 4; m++)
          aO[m] = *(const short8*)(Ap + (size_t)(m * 16 + li) * HD + (kt + 1) * 32 + kc * 8);
        bO = *(const short8*)(Wb0 + (size_t)li * HD + (kt + 1) * 32 + kc * 8);
#pragma unroll
        for (int m = 0; m < 4; m++)
          acc[m] = __builtin_amdgcn_mfma_f32_16x16x32_bf16(aE[m], bE, acc[m], 0, 0, 0);
        if (kt + 2 < 32) {
#pragma unroll
          for (int m = 0; m < 4; m++)
            aE[m] = *(const short8*)(Ap + (size_t)(m * 16 + li) * HD + (kt + 2) * 32 + kc * 8);
          bE = *(const short8*)(Wb0 + (size_t)li * HD + (kt + 2) * 32 + kc * 8);
        }
#pragma unroll
        for (int m = 0; m < 4; m++)
          acc[m] = __builtin_amdgcn_mfma_f32_16x16x32_bf16(aO[m], bO, acc[m], 0, 0, 0);
      }
#pragma unroll
      for (int m = 0; m < 4; m++)
#pragma unroll
        for (int r = 0; r < 4; r++)
          Gs[m * 16 + kc * 4 + r][w][li] = acc[m][r];
      __syncthreads();

      // cell0: add X0 (has x@Wih0^T + both biases), c in regs, write h bf16
      const float* X0t = X0 + (size_t)t * BB * GG;
      short* hdst = h0buf + (t & 1) * HSLOT;
      const int j = jb + cc;
#pragma unroll
      for (int r = 0; r < 4; r++) {
        int b = r * 16 + bq;
        float gi = Gs[b][0][cc] + X0t[(size_t)b * GG + j];
        float gf = Gs[b][1][cc] + X0t[(size_t)b * GG + HD + j];
        float gg = Gs[b][2][cc] + X0t[(size_t)b * GG + 2 * HD + j];
        float go = Gs[b][3][cc] + X0t[(size_t)b * GG + 3 * HD + j];
        float cn = sigf(gf) * creg[r] + sigf(gi) * tanhf(gg);
        float hn = sigf(go) * tanhf(cn);
        creg[r] = cn;
        hdst[b * HD + j] = f2bf(hn);
      }
    } else if (!isL0 && ph >= 1) {
      // ======== layer 1, step t: K=2048 over [h0(t) | h1(t-1)] ========
      const int t = ph - 1;
      const short* A0b = h0buf + (t & 1) * HSLOT;        // h0(t), written phase ph-1
      const short* A1b = H1b + (size_t)t * HSLOT;        // h1(t-1)
      f32x4 acc[4];
#pragma unroll
      for (int m = 0; m < 4; m++)
#pragma unroll
        for (int q = 0; q < 4; q++) acc[m][q] = 0.f;

      short8 aE[4], aO[4], bE, bO;
#pragma unroll
      for (int m = 0; m < 4; m++)
        aE[m] = *(const short8*)(A0b + (size_t)(m * 16 + li) * HD + kc * 8);
      bE = *(const short8*)(Wi1w + (size_t)li * HD + kc * 8);
#pragma unroll
      for (int kt = 0; kt < 64; kt += 2) {
        {
          const short* ab = (kt + 1 < 32) ? A0b : A1b;
          const short* wb = (kt + 1 < 32) ? Wi1w : Wh1w;
          int kk = (kt + 1) & 31;
#pragma unroll
          for (int m = 0; m < 4; m++)
            aO[m] = *(const short8*)(ab + (size_t)(m * 16 + li) * HD + kk * 32 + kc * 8);
          bO = *(const short8*)(wb + (size_t)li * HD + kk * 32 + kc * 8);
        }
#pragma unroll
        for (int m = 0; m < 4; m++)
          acc[m] = __builtin_amdgcn_mfma_f32_16x16x32_bf16(aE[m], bE, acc[m], 0, 0, 0);
        if (kt + 2 < 64) {
          const short* ab = (kt + 2 < 32) ? A0b : A1b;
          const short* wb = (kt + 2 < 32) ? Wi1w : Wh1w;
          int kk = (kt + 2) & 31;
#pragma unroll
          for (int m = 0; m < 4; m++)
            aE[m] = *(const short8*)(ab + (size_t)(m * 16 + li) * HD + kk * 32 + kc * 8);
          bE = *(const short8*)(wb + (size_t)li * HD + kk * 32 + kc * 8);
        }
#pragma unroll
        for (int m = 0; m < 4; m++)
          acc[m] = __builtin_amdgcn_mfma_f32_16x16x32_bf16(aO[m], bO, acc[m], 0, 0, 0);
      }
#pragma unroll
      for (int m = 0; m < 4; m++)
#pragma unroll
        for (int r = 0; r < 4; r++)
          Gs[m * 16 + kc * 4 + r][w][li] = acc[m][r];
      __syncthreads();

      // cell1: add combined bias, c in regs, write h1 -> H1 slot t+1 (bf16)
      short* hdst = H1b + (size_t)(t + 1) * HSLOT;
      const int j = jb + cc;
#pragma unroll
      for (int r = 0; r < 4; r++) {
        int b = r * 16 + bq;
        float gi = Gs[b][0][cc] + bsum1[j];
        float gf = Gs[b][1][cc] + bsum1[HD + j];
        float gg = Gs[b][2][cc] + bsum1[2 * HD + j];
        float go = Gs[b][3][cc] + bsum1[3 * HD + j];
        float cn = sigf(gf) * creg[r] + sigf(gi) * tanhf(gg);
        float hn = sigf(go) * tanhf(cn);
        creg[r] = cn;
        hdst[b * HD + j] = f2bf(hn);
      }
    }
    __threadfence();
    grid.sync();
  }
}

// ---------------- target logit from bf16 H1 ----------------
__global__ __launch_bounds__(256)
void tgt_logit_k(const short* __restrict__ H1log, const float* __restrict__ Wout,
                 const float* __restrict__ bout, const int* __restrict__ dec,
                 float* __restrict__ tl) {
  int gw = (blockIdx.x * 256 + threadIdx.x) >> 6;
  int lane = threadIdx.x & 63;
  if (gw >= NROWS) return;
  int tgt = dec[gw + 64];
  const short* hrow = H1log + (size_t)gw * HD;
  const float* wrow = Wout + (size_t)tgt * HD;
  float s = 0.f;
#pragma unroll
  for (int q = 0; q < 16; q++) {
    int k = lane + q * 64;
    s += bf2f(hrow[k]) * wrow[k];
  }
#pragma unroll
  for (int off = 32; off > 0; off >>= 1) s += __shfl_down(s, off);
  if (lane == 0) tl[gw] = s + bout[tgt];
}

// ---------------- fused logits MFMA GEMM + online LSE (validated round 2) ----
__global__ __launch_bounds__(256)
void lse_mfma_k(const short* __restrict__ H1log, const short* __restrict__ WoutB,
                const float* __restrict__ bout, float* __restrict__ m_part,
                float* __restrict__ s_part) {
  __shared__ short lds_a[128 * 64];
  __shared__ short lds_b[128 * 64];
  f32x4 acc[4][4];
#pragma unroll
  for (int m = 0; m < 4; m++)
#pragma unroll
    for (int n = 0; n < 4; n++)
#pragma unroll
      for (int q = 0; q < 4; q++) acc[m][n][q] = 0.f;

  mfma_loop<16>(H1log + (size_t)blockIdx.x * 128 * HD, HD,
                WoutB + (size_t)blockIdx.y * 128 * HD, HD, lds_a, lds_b, acc);

  const int l = threadIdx.x & 63;
  const int w = threadIdx.x >> 6;
  const int wm = w >> 1, wn = w & 1;
  const int colbase = blockIdx.y * 128 + wn * 64 + (l & 15);
  float bo[4];
#pragma unroll
  for (int n = 0; n < 4; n++) bo[n] = bout[colbase + n * 16];
  const int ch = blockIdx.y * 2 + wn;

#pragma unroll
  for (int m = 0; m < 4; m++) {
#pragma unroll
    for (int r = 0; r < 4; r++) {
      float v0 = acc[m][0][r] + bo[0];
      float v1 = acc[m][1][r] + bo[1];
      float v2 = acc[m][2][r] + bo[2];
      float v3 = acc[m][3][r] + bo[3];
      float mx = fmaxf(fmaxf(v0, v1), fmaxf(v2, v3));
      float s = __expf(v0 - mx) + __expf(v1 - mx) + __expf(v2 - mx) + __expf(v3 - mx);
#pragma unroll
      for (int off = 1; off < 16; off <<= 1) {
        float mo = __shfl_xor(mx, off);
        float so = __shfl_xor(s, off);
        float nm = fmaxf(mx, mo);
        s = s * __expf(mx - nm) + so * __expf(mo - nm);
        mx = nm;
      }
      if ((l & 15) == 0) {
        int row = blockIdx.x * 128 + wm * 64 + m * 16 + (l >> 4) * 4 + r;
        m_part[(size_t)ch * MPAD + row] = mx;
        s_part[(size_t)ch * MPAD + row] = s;
      }
    }
  }
}

// ---------------- per-row LSE merge + loss atomicAdd ----------------
__global__ __launch_bounds__(256)
void row_lse_k(const float* __restrict__ m_part, const float* __restrict__ s_part,
               const float* __restrict__ tl, float* __restrict__ out) {
  int row = blockIdx.x * 256 + threadIdx.x;
  float loss = 0.f;
  if (row < NROWS) {
    float M = -INFINITY, S = 0.f;
    for (int ch = 0; ch < NCH; ch++) {
      float m = m_part[(size_t)ch * MPAD + row];
      float s = s_part[(size_t)ch * MPAD + row];
      float nm = fmaxf(M, m);
      S = S * __expf(M - nm) + s * __expf(m - nm);
      M = nm;
    }
    loss = M + logf(S) - tl[row];
  }
  __shared__ float red[256];
  red[threadIdx.x] = loss;
  __syncthreads();
  for (int s = 128; s > 0; s >>= 1) {
    if (threadIdx.x < s) red[threadIdx.x] += red[threadIdx.x + s];
    __syncthreads();
  }
  if (threadIdx.x == 0) atomicAdd(out, red[0]);
}

extern "C" void kernel_launch(void* const* d_in, const int* in_sizes, int n_in,
                              void* d_out, int out_size, void* d_ws, size_t ws_size,
                              hipStream_t stream) {
  const int*   dec  = (const int*)  d_in[0];
  const float* h0   = (const float*)d_in[2];
  const float* c0   = (const float*)d_in[3];
  const float* emb  = (const float*)d_in[4];
  const float* Wih0 = (const float*)d_in[5];
  const float* Whh0 = (const float*)d_in[6];
  const float* bih0 = (const float*)d_in[7];
  const float* bhh0 = (const float*)d_in[8];
  const float* Wih1 = (const float*)d_in[9];
  const float* Whh1 = (const float*)d_in[10];
  const float* bih1 = (const float*)d_in[11];
  const float* bhh1 = (const float*)d_in[12];
  const float* Wout = (const float*)d_in[13];
  const float* bout = (const float*)d_in[14];
  float* out = (float*)d_out;

  float* ws = (float*)d_ws;
  float* X0     = ws;                                   // 4096*4096 f
  float* m_part = X0 + (size_t)MPAD * GG;               // 500*4096 f
  float* s_part = m_part + (size_t)NCH * MPAD;          // 500*4096 f
  float* tl     = s_part + (size_t)NCH * MPAD;          // 4096 f
  float* bsum1  = tl + MPAD;                            // 4096 f
  short* H1b    = (short*)(bsum1 + GG);                 // 64 slots: 65536 + 4096*1024 sh
  short* WoutB  = H1b + HSLOT + (size_t)MPAD * HD;      // 32000*1024 sh
  short* Wih0B  = WoutB + (size_t)VV * HD;              // 4096*512 sh
  short* XembB  = Wih0B + (size_t)GG * ED;              // 4096*512 sh
  short* Wh0b   = XembB + (size_t)MPAD * ED;            // 4096*1024 sh
  short* Wi1b   = Wh0b + (size_t)GG * HD;               // 4096*1024 sh
  short* Wh1b   = Wi1b + (size_t)GG * HD;               // 4096*1024 sh
  short* h0buf  = Wh1b + (size_t)GG * HD;               // 2*64*1024 sh
  short* H1log  = H1b + HSLOT;                          // logits A view (4032+64pad rows)

  cvt_f2b_k<<<(VV * HD) / 1024, 256, 0, stream>>>(Wout, WoutB);
  cvt_f2b_k<<<(GG * ED) / 1024, 256, 0, stream>>>(Wih0, Wih0B);
  cvt_f2b_k<<<(GG * HD) / 1024, 256, 0, stream>>>(Whh0, Wh0b);
  cvt_f2b_k<<<(GG * HD) / 1024, 256, 0, stream>>>(Wih1, Wi1b);
  cvt_f2b_k<<<(GG * HD) / 1024, 256, 0, stream>>>(Whh1, Wh1b);
  gather_emb_k<<<(MPAD * ED / 4) / 256, 256, 0, stream>>>(dec, emb, XembB);
  init_state2_k<<<256, 256, 0, stream>>>(h0, h0buf, H1b);
  bias_sum_k<<<16, 256, 0, stream>>>(bih1, bhh1, bsum1);
  pad_h1b_k<<<64, 256, 0, stream>>>(H1log + (size_t)NROWS * HD);
  zero_out_k<<<1, 64, 0, stream>>>(out);
  x0_mfma_k<<<dim3(MPAD / 128, GG / 128), 256, 0, stream>>>(XembB, Wih0B, bih0, bhh0, X0);

  void* args[] = {&X0, &bsum1, &Wh0b, &Wi1b, &Wh1b, &h0buf, &H1b, (void*)&c0};
  hipLaunchCooperativeKernel((void*)recurrence_k, dim3(128), dim3(256), args, 0, stream);

  tgt_logit_k<<<(NROWS * 64 + 255) / 256, 256, 0, stream>>>(H1log, Wout, bout, dec, tl);
  lse_mfma_k<<<dim3(MPAD / 128, VV / 128), 256, 0, stream>>>(H1log, WoutB, bout, m_part, s_part);
  row_lse_k<<<MPAD / 256, 256, 0, stream>>>(m_part, s_part, tl, out);
}